// Round 7
// baseline (217.757 us; speedup 1.0000x reference)
//
#include <hip/hip_runtime.h>
#include <hip/hip_bf16.h>
#include <stdint.h>

#define NB 4096
#define NCOL 100
#define NCOND 64
#define NTOTAL 6400
#define NRODT 1600
#define NEST 160
#define NFOR 100
#define NHID 128
#define NCLS 10
#define GEPS 1e-5f

typedef __attribute__((ext_vector_type(8))) short short8;
typedef __attribute__((ext_vector_type(4))) float floatx4;

// round-half-up f32->bf16: 2 VALU ops; tie-only difference vs RNE
__device__ __forceinline__ unsigned f2bfu(float x) {
  union { float f; unsigned u; } v; v.f = x;
  return (v.u + 0x8000u) >> 16;
}
__device__ __forceinline__ float bf2f(unsigned short u) {
  union { unsigned u; float f; } v; v.u = ((unsigned)u) << 16;
  return v.f;
}

// all-reduce sum over the 16-lane DPP row -- VALU pipe, no LDS.
__device__ __forceinline__ float rowsum16(float v) {
  union { float f; int i; } a, t;
  a.f = v;
  t.i = __builtin_amdgcn_update_dpp(0, a.i, 0x128, 0xf, 0xf, true); a.f += t.f; // ror:8
  t.i = __builtin_amdgcn_update_dpp(0, a.i, 0x124, 0xf, 0xf, true); a.f += t.f; // ror:4
  t.i = __builtin_amdgcn_update_dpp(0, a.i, 0x122, 0xf, 0xf, true); a.f += t.f; // ror:2
  t.i = __builtin_amdgcn_update_dpp(0, a.i, 0x121, 0xf, 0xf, true); a.f += t.f; // ror:1
  return a.f;
}

// broadcast the value of each 16-lane group's leader (lane & 0x30) to the
// whole group: ds_swizzle BitMode, and_mask=0x10 (keeps bit4 within 32-half).
__device__ __forceinline__ float bcast16(float v) {
  union { float f; int i; } a; a.f = v;
  a.i = __builtin_amdgcn_ds_swizzle(a.i, 0x0010);
  return a.f;
}

// 1-bit LDS row swizzle key: XOR of byte-bit4. Row stride 320 B = 10*32 B, so
// the 32 B XOR window divides the stride -> bijective within each row.
__device__ __forceinline__ int lkey(int row) {
  return ((row ^ (row >> 2)) & 1) << 4;
}

// ---------------------------------------------------------------------------
// K01: merged prep kernel (single launch). Unchanged (proven).
//  blocks [0,1600)    : k1 -- ConditionGeneration+perm+phi_2 -> exp(w)^T bf16
//  blocks [1600,1702) : k0 -- fragment-pack Bf / W1f / W2f (identity k-map)
//  blocks [1702,1705) : zero d_out
// ---------------------------------------------------------------------------
__global__ __launch_bounds__(256) void k01_prep(
    const float* __restrict__ x, const float* __restrict__ w1,
    const float* __restrict__ b1, const int* __restrict__ perm,
    const float* __restrict__ gn1w, const float* __restrict__ gn1b,
    const float* __restrict__ c2w, const float* __restrict__ c2b,
    const float* __restrict__ gn2w, const float* __restrict__ gn2b,
    const float* __restrict__ c3w, const float* __restrict__ c3b,
    const float* __restrict__ E, const int* __restrict__ swr,
    const float* __restrict__ fc1w, const float* __restrict__ fc2w,
    unsigned short* __restrict__ wT,
    unsigned short* __restrict__ Bf, unsigned short* __restrict__ W1f,
    unsigned short* __restrict__ W2f, float* __restrict__ out)
{
  __shared__ float xl[64 * NCOL];          // k1 path only (25.6 KB)
  __shared__ int ridx[NEST];               // k0 path only
  const int tid = threadIdx.x;
  const int blk = blockIdx.x;

  if (blk < 1600) {
    // ---------------- k1: phi_2 logits -> exp -> bf16, transposed ----------
    const int b0 = (blk & 63) * 64;
    const int g  = (blk >> 6) * 64 + (tid >> 2);
    const int i4 = tid & 3;
    for (int i = tid; i < 64 * NCOL; i += 256)
      xl[i] = x[(size_t)b0 * NCOL + i];
    __syncthreads();

    const int4 p4 = *(const int4*)(perm + 4 * g);
    const int pv[4] = {p4.x, p4.y, p4.z, p4.w};
    float w1v[4], b1v[4];
    int pc[4];
#pragma unroll
    for (int i = 0; i < 4; i++) {
      unsigned p = (unsigned)pv[i];
      unsigned j = p / 100u;
      unsigned cc = p - j * 100u;
      pc[i] = (int)cc;
      w1v[i] = w1[cc * NCOND + j];
      b1v[i] = b1[cc * NCOND + j];
    }
    const float4 g1w = *(const float4*)(gn1w + 4 * g);
    const float4 g1b = *(const float4*)(gn1b + 4 * g);
    const float4 cw0 = *(const float4*)(c2w + 16 * g);
    const float4 cw1 = *(const float4*)(c2w + 16 * g + 4);
    const float4 cw2 = *(const float4*)(c2w + 16 * g + 8);
    const float4 cw3 = *(const float4*)(c2w + 16 * g + 12);
    const float4 cbv = *(const float4*)(c2b + 4 * g);
    const float4 g2w = *(const float4*)(gn2w + 4 * g);
    const float4 g2b = *(const float4*)(gn2b + 4 * g);
    const float4 c3v = *(const float4*)(c3w + 4 * g);
    const float c3bv = c3b[g];

    for (int k = 0; k < 4; k++) {
      float v4[4];
#pragma unroll
      for (int j = 0; j < 4; j++) {
        const int bb = k * 16 + i4 * 4 + j;
        float O[4];
#pragma unroll
        for (int i = 0; i < 4; i++) {
          float a = xl[bb * NCOL + pc[i]] * w1v[i] + b1v[i];
          O[i] = 1.0f / (1.0f + __expf(-a));
        }
        float mu = 0.25f * (O[0] + O[1] + O[2] + O[3]);
        float d[4], var = 0.f;
#pragma unroll
        for (int i = 0; i < 4; i++) { d[i] = O[i] - mu; var += d[i] * d[i]; }
        float rs = rsqrtf(0.25f * var + GEPS);
        float xn0 = d[0] * rs * g1w.x + g1b.x;
        float xn1 = d[1] * rs * g1w.y + g1b.y;
        float xn2 = d[2] * rs * g1w.z + g1b.z;
        float xn3 = d[3] * rs * g1w.w + g1b.w;
        float h[4];
        h[0] = xn0*cw0.x + xn1*cw1.x + xn2*cw2.x + xn3*cw3.x + cbv.x;
        h[1] = xn0*cw0.y + xn1*cw1.y + xn2*cw2.y + xn3*cw3.y + cbv.y;
        h[2] = xn0*cw0.z + xn1*cw1.z + xn2*cw2.z + xn3*cw3.z + cbv.z;
        h[3] = xn0*cw0.w + xn1*cw1.w + xn2*cw2.w + xn3*cw3.w + cbv.w;
#pragma unroll
        for (int i = 0; i < 4; i++) h[i] = fmaxf(h[i], 0.f);
        float mu2 = 0.25f * (h[0] + h[1] + h[2] + h[3]);
        float e[4], var2 = 0.f;
#pragma unroll
        for (int i = 0; i < 4; i++) { e[i] = h[i] - mu2; var2 += e[i] * e[i]; }
        float rs2 = rsqrtf(0.25f * var2 + GEPS);
        float hn0 = e[0] * rs2 * g2w.x + g2b.x;
        float hn1 = e[1] * rs2 * g2w.y + g2b.y;
        float hn2 = e[2] * rs2 * g2w.z + g2b.z;
        float hn3 = e[3] * rs2 * g2w.w + g2b.w;
        v4[j] = hn0*c3v.x + hn1*c3v.y + hn2*c3v.z + hn3*c3v.w + c3bv;
      }
      // store exp(logit): k3's softmax numerator, once per unique (g,b)
      uint2 pk;
      pk.x = f2bfu(__expf(v4[0])) | (f2bfu(__expf(v4[1])) << 16);
      pk.y = f2bfu(__expf(v4[2])) | (f2bfu(__expf(v4[3])) << 16);
      *(uint2*)(wT + (size_t)g * NB + b0 + k * 16 + i4 * 4) = pk;
    }
  } else if (blk < 1600 + NFOR) {
    // ---------------- k0: Bf fragment pack ----------------
    const int fblk = blk - 1600;
    if (tid < NEST) ridx[tid] = swr[fblk * NEST + tid];
    __syncthreads();
    for (int m = tid; m < 2560; m += 256) {        // m = (n*5+kc)*64 + lane
      int lane = m & 63, rest = m >> 6;
      int kc = rest % 5, n = rest / 5;
      int q = lane >> 4, c = lane & 15;
      int e0 = kc * 32 + q * 8;
      int h = n * 16 + c;
      union { unsigned short v[8]; uint4 u; } t;
#pragma unroll
      for (int j = 0; j < 8; j++)
        t.v[j] = (unsigned short)f2bfu(E[(size_t)ridx[e0 + j] * NHID + h]);
      *(uint4*)(Bf + (size_t)fblk * 20480 + (size_t)m * 8) = t.u;
    }
  } else if (blk == 1600 + NFOR) {
    // ---------------- k0: W1f (identity k-map) ----------------
    for (int m = tid; m < 2048; m += 256) {        // m = (n*4+kc)*64 + lane
      int lane = m & 63, rest = m >> 6;
      int kc = rest & 3, n = rest >> 2;
      int q = lane >> 4, c = lane & 15;
      int k0 = kc * 32 + q * 8;
      int o = n * 16 + c;
      union { unsigned short v[8]; uint4 u; } t;
#pragma unroll
      for (int j = 0; j < 8; j++)
        t.v[j] = (unsigned short)f2bfu(fc1w[(size_t)(k0 + j) * NHID + o]);
      *(uint4*)(W1f + (size_t)m * 8) = t.u;
    }
  } else if (blk == 1601 + NFOR) {
    // ---------------- k0: W2f (identity k-map) ----------------
    for (int m = tid; m < 256; m += 256) {         // m = kc*64 + lane
      int lane = m & 63, kc = m >> 6;
      int q = lane >> 4, c = lane & 15;
      int k0 = kc * 32 + q * 8;
      union { unsigned short v[8]; uint4 u; } t;
#pragma unroll
      for (int j = 0; j < 8; j++)
        t.v[j] = (unsigned short)f2bfu(c < NCLS ? fc2w[(size_t)(k0 + j) * NCLS + c] : 0.f);
      *(uint4*)(W2f + (size_t)m * 8) = t.u;
    }
  } else {
    // ---------------- zero d_out (3 blocks) ----------------
    const int z = blk - (1602 + NFOR);
    float4 zz = make_float4(0.f, 0.f, 0.f, 0.f);
    for (int i = z * 256 + tid; i < NB * NCLS / 4; i += 3 * 256)
      ((float4*)out)[i] = zz;
  }
}

// ---------------------------------------------------------------------------
// K3 (R24): R23 body + LDS 43008 -> 40960 B via stride-160 + 1-bit XOR row
//  swizzle -> 4 blocks/CU (was 3, LDS-capped). Mechanism: 44% of cycles are
//  idle waits at ~2-3 waves/SIMD; +33% resident waves is the cheapest TLP
//  lever. The 168-pad existed only for bank spread; key(row)=((row^row>>2)&1)
//  <<4 XOR on byte-bit4 recovers it: GEMM b128 reads 8-group balanced
//  (optimal), gather writes 2-way (free), Fn/H2 scalar ~4-way (as before).
//  Key commutes with all +n*32/+kc*64 offsets -> one pre-XOR'd base per
//  access family, ~20 extra VALU/wave total.
//  Straight-line body, statically-indexed register arrays only (R18 lesson).
// ---------------------------------------------------------------------------
__global__ __launch_bounds__(256, 4) void k3_mfma(
    const unsigned short* __restrict__ wT,    // [1600][B] bf16 exp(logits)^T
    const int* __restrict__ swr,
    const unsigned short* __restrict__ Bf,    // [f][8][5][64][8]
    const unsigned short* __restrict__ W1f,   // [8][4][64][8]
    const unsigned short* __restrict__ W2f,   // [4][64][8]
    const float* __restrict__ ln1w, const float* __restrict__ ln1b,
    const float* __restrict__ fc1b,
    const float* __restrict__ ln2w, const float* __restrict__ ln2b,
    const float* __restrict__ fc2b,
    float* __restrict__ out)
{
  __shared__ unsigned short lsA[128 * 160];   // 40960 B: 4 blocks/CU exactly
  char* const lsb = (char*)lsA;
  const int T1 = 64 * 320;                    // byte offset of tile-1 rows

  const int tid = threadIdx.x;
  // ---- XCD-chunked swizzle: id -> (bx, f) ----
  const int id  = blockIdx.y * 32 + blockIdx.x;   // linear dispatch id, [0,3200)
  const int xcd = id & 7;
  const int pos = id >> 3;                        // [0,400)
  const int f   = pos >> 2;                       // [0,100)
  const int b0  = (xcd * 4 + (pos & 3)) * 128;    // bx in [4*xcd, 4*xcd+4)
  const int lane = tid & 63;
  const int wv = __builtin_amdgcn_readfirstlane(tid >> 6);  // wave-uniform SGPR
  const int c = lane & 15, q = lane >> 4;

  // ---- gather phase: wave wv covers e in [40wv,40wv+40) for BOTH tiles ----
  // 2 chunks of 20 indices; all indices hoisted (wave-uniform -> s_load).
  // LDS row = lane (t0) / 64+lane (t1); note lkey(64+r)==lkey(r).
  {
    const unsigned short* wbase = wT + b0 + lane;
    const int* swf = swr + f * NEST + wv * 40;
    int idx[40];
#pragma unroll
    for (int e = 0; e < 40; e++) idx[e] = swf[e];

    const int ub = lane * 320 + wv * 80;      // byte offset: row lane, col 40wv
    const int kx = lkey(lane);

#pragma unroll
    for (int h = 0; h < 2; h++) {
      unsigned short u0[20], u1[20];
#pragma unroll
      for (int e = 0; e < 20; e++) {
        const unsigned short* p = wbase + (size_t)idx[h * 20 + e] * NB;
        u0[e] = p[0];
        u1[e] = p[64];
      }
      // pack & store shorts [20h, 20h+20) of rows lane (t0) / lane+64 (t1)
#define MKU(a, i) ((unsigned)(a)[i] | ((unsigned)(a)[i + 1] << 16))
      if (h == 0) {
        uint4 a0 = {MKU(u0,0), MKU(u0,2), MKU(u0,4), MKU(u0,6)};
        uint4 b0v = {MKU(u0,8), MKU(u0,10), MKU(u0,12), MKU(u0,14)};
        uint2 c0 = {MKU(u0,16), MKU(u0,18)};
        *(uint4*)(lsb + ((ub +  0) ^ kx)) = a0;
        *(uint4*)(lsb + ((ub + 16) ^ kx)) = b0v;
        *(uint2*)(lsb + ((ub + 32) ^ kx)) = c0;
        uint4 a1 = {MKU(u1,0), MKU(u1,2), MKU(u1,4), MKU(u1,6)};
        uint4 b1v = {MKU(u1,8), MKU(u1,10), MKU(u1,12), MKU(u1,14)};
        uint2 c1 = {MKU(u1,16), MKU(u1,18)};
        *(uint4*)(lsb + T1 + ((ub +  0) ^ kx)) = a1;
        *(uint4*)(lsb + T1 + ((ub + 16) ^ kx)) = b1v;
        *(uint2*)(lsb + T1 + ((ub + 32) ^ kx)) = c1;
      } else {
        uint2 a0 = {MKU(u0,0), MKU(u0,2)};
        uint4 b0v = {MKU(u0,4), MKU(u0,6), MKU(u0,8), MKU(u0,10)};
        uint4 c0 = {MKU(u0,12), MKU(u0,14), MKU(u0,16), MKU(u0,18)};
        *(uint2*)(lsb + ((ub + 40) ^ kx)) = a0;
        *(uint4*)(lsb + ((ub + 48) ^ kx)) = b0v;
        *(uint4*)(lsb + ((ub + 64) ^ kx)) = c0;
        uint2 a1 = {MKU(u1,0), MKU(u1,2)};
        uint4 b1v = {MKU(u1,4), MKU(u1,6), MKU(u1,8), MKU(u1,10)};
        uint4 c1 = {MKU(u1,12), MKU(u1,14), MKU(u1,16), MKU(u1,18)};
        *(uint2*)(lsb + T1 + ((ub + 40) ^ kx)) = a1;
        *(uint4*)(lsb + T1 + ((ub + 48) ^ kx)) = b1v;
        *(uint4*)(lsb + T1 + ((ub + 64) ^ kx)) = c1;
      }
#undef MKU
    }
  }

  // ---- prefetch GEMM1 kc=0 B-fragments (independent of gather/barrier) ----
  const unsigned short* bbase = Bf + (size_t)f * 20480 + lane * 8;
  short8 bp[8];
#pragma unroll
  for (int n = 0; n < 8; n++)
    bp[n] = *(const short8*)(bbase + n * 2560);

  __syncthreads();                     // the ONLY barrier

  // ---- GEMM1: (exp-ws)[128x160] @ Ep[160x128]; B loaded once per 2 tiles --
  //      + ones-column MFMA computing the softmax denominators
  // A-fragment base: row wv*16+c, byte q*16 within row, pre-XOR'd once;
  // kc offsets are +kc*64 bytes (no bit4 -> commute with the XOR).
  const int row0 = wv * 16 + c;
  const unsigned short* pa0 =
      (const unsigned short*)(lsb + ((row0 * 320 + q * 16) ^ lkey(row0)));
  const unsigned short* pa1 = (const unsigned short*)((const char*)pa0 + T1);
  const short onev = (c == 0) ? (short)0x3F80 : (short)0;  // bf16 1.0 in col 0
  short8 bones;
#pragma unroll
  for (int j = 0; j < 8; j++) bones[j] = onev;

  floatx4 acc0[8], acc1[8];
  floatx4 accs0 = (floatx4){0.f, 0.f, 0.f, 0.f};
  floatx4 accs1 = (floatx4){0.f, 0.f, 0.f, 0.f};
  __builtin_amdgcn_s_setprio(1);
  {
    short8 a0 = *(const short8*)(pa0);
    short8 a1 = *(const short8*)(pa1);
#pragma unroll
    for (int n = 0; n < 8; n++) {
      acc0[n] = __builtin_amdgcn_mfma_f32_16x16x32_bf16(a0, bp[n], (floatx4){0.f,0.f,0.f,0.f}, 0, 0, 0);
      acc1[n] = __builtin_amdgcn_mfma_f32_16x16x32_bf16(a1, bp[n], (floatx4){0.f,0.f,0.f,0.f}, 0, 0, 0);
    }
    accs0 = __builtin_amdgcn_mfma_f32_16x16x32_bf16(a0, bones, accs0, 0, 0, 0);
    accs1 = __builtin_amdgcn_mfma_f32_16x16x32_bf16(a1, bones, accs1, 0, 0, 0);
  }
#pragma unroll
  for (int kc = 1; kc < 5; kc++) {
    short8 a0 = *(const short8*)(pa0 + kc * 32);
    short8 a1 = *(const short8*)(pa1 + kc * 32);
#pragma unroll
    for (int n = 0; n < 8; n++) {
      short8 b = *(const short8*)(bbase + n * 2560 + kc * 512);
      acc0[n] = __builtin_amdgcn_mfma_f32_16x16x32_bf16(a0, b, acc0[n], 0, 0, 0);
      acc1[n] = __builtin_amdgcn_mfma_f32_16x16x32_bf16(a1, b, acc1[n], 0, 0, 0);
    }
    accs0 = __builtin_amdgcn_mfma_f32_16x16x32_bf16(a0, bones, accs0, 0, 0, 0);
    accs1 = __builtin_amdgcn_mfma_f32_16x16x32_bf16(a1, bones, accs1, 0, 0, 0);
  }
  __builtin_amdgcn_s_setprio(0);

  // ---- LN1 (both tiles): LN(x/s) == (x-mu)*rsqrt(var + eps*s^2) ----
  {
    float lw[8], lb[8];
#pragma unroll
    for (int n = 0; n < 8; n++) { lw[n] = ln1w[n * 16 + c]; lb[n] = ln1b[n * 16 + c]; }
#pragma unroll
    for (int rr = 0; rr < 4; rr++) {
      {
        float st = bcast16(accs0[rr]);         // denominator, row q*4+rr (t0)
        float s1 = 0.f, s2 = 0.f;
#pragma unroll
        for (int n = 0; n < 8; n++) { float v = acc0[n][rr]; s1 += v; s2 += v * v; }
        s1 = rowsum16(s1);
        s2 = rowsum16(s2);
        float mu = s1 * (1.f / 128.f);
        float var = fmaxf(s2 * (1.f / 128.f) - mu * mu, 0.f);
        float rs = rsqrtf(var + GEPS * st * st);
#pragma unroll
        for (int n = 0; n < 8; n++)
          acc0[n][rr] = (acc0[n][rr] - mu) * rs * lw[n] + lb[n];
      }
      {
        float st = bcast16(accs1[rr]);         // denominator, row q*4+rr (t1)
        float s1 = 0.f, s2 = 0.f;
#pragma unroll
        for (int n = 0; n < 8; n++) { float v = acc1[n][rr]; s1 += v; s2 += v * v; }
        s1 = rowsum16(s1);
        s2 = rowsum16(s2);
        float mu = s1 * (1.f / 128.f);
        float var = fmaxf(s2 * (1.f / 128.f) - mu * mu, 0.f);
        float rs = rsqrtf(var + GEPS * st * st);
#pragma unroll
        for (int n = 0; n < 8; n++)
          acc1[n][rr] = (acc1[n][rr] - mu) * rs * lw[n] + lb[n];
      }
    }
  }

  // ---- Fn -> lsA (A-layout bf16, wave-private rows; no barrier needed) ----
  // write row wv*16+q*4+rr, col n*16+c: base (row*320 + 2c)^key, + n*32.
#pragma unroll
  for (int rr = 0; rr < 4; rr++) {
    const int rowr = wv * 16 + q * 4 + rr;
    char* wb = lsb + ((rowr * 320 + 2 * c) ^ lkey(rowr));
#pragma unroll
    for (int n = 0; n < 8; n++) {
      *(unsigned short*)(wb + n * 32)      = (unsigned short)f2bfu(acc0[n][rr]);
      *(unsigned short*)(wb + T1 + n * 32) = (unsigned short)f2bfu(acc1[n][rr]);
    }
  }

  // ---- GEMM2: H = Fn[128x128] @ fc1w[128x128]; W1f loaded once per 2 tiles -
  {
    short8 a00 = *(const short8*)(pa0);
    short8 a01 = *(const short8*)(pa0 + 32);
    short8 a02 = *(const short8*)(pa0 + 64);
    short8 a03 = *(const short8*)(pa0 + 96);
    short8 a10 = *(const short8*)(pa1);
    short8 a11 = *(const short8*)(pa1 + 32);
    short8 a12 = *(const short8*)(pa1 + 64);
    short8 a13 = *(const short8*)(pa1 + 96);
    const unsigned short* w1p = W1f + lane * 8;
    __builtin_amdgcn_s_setprio(1);
#pragma unroll
    for (int n = 0; n < 8; n++) {
      const unsigned short* wp = w1p + n * 2048;
      short8 b0v = *(const short8*)(wp);
      short8 b1v = *(const short8*)(wp + 512);
      short8 b2v = *(const short8*)(wp + 1024);
      short8 b3v = *(const short8*)(wp + 1536);
      floatx4 t0 = __builtin_amdgcn_mfma_f32_16x16x32_bf16(a00, b0v, (floatx4){0.f,0.f,0.f,0.f}, 0, 0, 0);
      t0 = __builtin_amdgcn_mfma_f32_16x16x32_bf16(a01, b1v, t0, 0, 0, 0);
      t0 = __builtin_amdgcn_mfma_f32_16x16x32_bf16(a02, b2v, t0, 0, 0, 0);
      t0 = __builtin_amdgcn_mfma_f32_16x16x32_bf16(a03, b3v, t0, 0, 0, 0);
      floatx4 t1 = __builtin_amdgcn_mfma_f32_16x16x32_bf16(a10, b0v, (floatx4){0.f,0.f,0.f,0.f}, 0, 0, 0);
      t1 = __builtin_amdgcn_mfma_f32_16x16x32_bf16(a11, b1v, t1, 0, 0, 0);
      t1 = __builtin_amdgcn_mfma_f32_16x16x32_bf16(a12, b2v, t1, 0, 0, 0);
      t1 = __builtin_amdgcn_mfma_f32_16x16x32_bf16(a13, b3v, t1, 0, 0, 0);
      acc0[n] = t0;
      acc1[n] = t1;
    }
    __builtin_amdgcn_s_setprio(0);
  }

  // ---- bias + ReLU + LN2 (both tiles, DPP row-reduce) ----
  {
    float fb[8], lw[8], lb[8];
#pragma unroll
    for (int n = 0; n < 8; n++) {
      fb[n] = fc1b[n * 16 + c];
      lw[n] = ln2w[n * 16 + c]; lb[n] = ln2b[n * 16 + c];
    }
#pragma unroll
    for (int rr = 0; rr < 4; rr++) {
      {
#pragma unroll
        for (int n = 0; n < 8; n++) acc0[n][rr] = fmaxf(acc0[n][rr] + fb[n], 0.f);
        float s1 = 0.f, s2 = 0.f;
#pragma unroll
        for (int n = 0; n < 8; n++) { float v = acc0[n][rr]; s1 += v; s2 += v * v; }
        s1 = rowsum16(s1);
        s2 = rowsum16(s2);
        float mu = s1 * (1.f / 128.f);
        float var = fmaxf(s2 * (1.f / 128.f) - mu * mu, 0.f);
        float rs = rsqrtf(var + GEPS);
#pragma unroll
        for (int n = 0; n < 8; n++)
          acc0[n][rr] = (acc0[n][rr] - mu) * rs * lw[n] + lb[n];
      }
      {
#pragma unroll
        for (int n = 0; n < 8; n++) acc1[n][rr] = fmaxf(acc1[n][rr] + fb[n], 0.f);
        float s1 = 0.f, s2 = 0.f;
#pragma unroll
        for (int n = 0; n < 8; n++) { float v = acc1[n][rr]; s1 += v; s2 += v * v; }
        s1 = rowsum16(s1);
        s2 = rowsum16(s2);
        float mu = s1 * (1.f / 128.f);
        float var = fmaxf(s2 * (1.f / 128.f) - mu * mu, 0.f);
        float rs = rsqrtf(var + GEPS);
#pragma unroll
        for (int n = 0; n < 8; n++)
          acc1[n][rr] = (acc1[n][rr] - mu) * rs * lw[n] + lb[n];
      }
    }
  }

  // ---- H2 -> lsA (A-layout, wave-private rows; no barrier) ----
#pragma unroll
  for (int rr = 0; rr < 4; rr++) {
    const int rowr = wv * 16 + q * 4 + rr;
    char* wb = lsb + ((rowr * 320 + 2 * c) ^ lkey(rowr));
#pragma unroll
    for (int n = 0; n < 8; n++) {
      *(unsigned short*)(wb + n * 32)      = (unsigned short)f2bfu(acc0[n][rr]);
      *(unsigned short*)(wb + T1 + n * 32) = (unsigned short)f2bfu(acc1[n][rr]);
    }
  }

  // ---- fc2 (16-col padded tile), W2f loaded once per 2 tiles ----
  floatx4 o40 = (floatx4){0.f, 0.f, 0.f, 0.f};
  floatx4 o41 = (floatx4){0.f, 0.f, 0.f, 0.f};
#pragma unroll
  for (int kc = 0; kc < 4; kc++) {
    short8 a0 = *(const short8*)(pa0 + kc * 32);
    short8 a1 = *(const short8*)(pa1 + kc * 32);
    short8 b = *(const short8*)(W2f + kc * 512 + lane * 8);
    o40 = __builtin_amdgcn_mfma_f32_16x16x32_bf16(a0, b, o40, 0, 0, 0);
    o41 = __builtin_amdgcn_mfma_f32_16x16x32_bf16(a1, b, o41, 0, 0, 0);
  }
  if (c < NCLS) {
    float bias = fc2b[c];
#pragma unroll
    for (int rr = 0; rr < 4; rr++) {
      atomicAdd(out + (size_t)(b0 + wv * 16 + q * 4 + rr) * NCLS + c,
                (o40[rr] + bias) * 0.01f);
      atomicAdd(out + (size_t)(b0 + 64 + wv * 16 + q * 4 + rr) * NCLS + c,
                (o41[rr] + bias) * 0.01f);
    }
  }
}

// ---------------------------------------------------------------------------
extern "C" void kernel_launch(void* const* d_in, const int* in_sizes, int n_in,
                              void* d_out, int out_size, void* d_ws, size_t ws_size,
                              hipStream_t stream)
{
  (void)in_sizes; (void)n_in; (void)ws_size; (void)out_size;
  const float* x    = (const float*)d_in[0];
  const float* w1   = (const float*)d_in[1];
  const float* b1   = (const float*)d_in[2];
  const int*   perm = (const int*)d_in[3];
  const float* gn1w = (const float*)d_in[4];
  const float* gn1b = (const float*)d_in[5];
  const float* c2w  = (const float*)d_in[6];
  const float* c2b  = (const float*)d_in[7];
  const float* gn2w = (const float*)d_in[8];
  const float* gn2b = (const float*)d_in[9];
  const float* c3w  = (const float*)d_in[10];
  const float* c3b  = (const float*)d_in[11];
  const int*   swr  = (const int*)d_in[12];
  const float* E    = (const float*)d_in[13];
  const float* ln1w = (const float*)d_in[14];
  const float* ln1b = (const float*)d_in[15];
  const float* fc1w = (const float*)d_in[16];
  const float* fc1b = (const float*)d_in[17];
  const float* ln2w = (const float*)d_in[18];
  const float* ln2b = (const float*)d_in[19];
  const float* fc2w = (const float*)d_in[20];
  const float* fc2b = (const float*)d_in[21];
  float* out = (float*)d_out;

  // workspace layout:
  //   [0, 13.1MB)       : wT exp-logits bf16 [1600][B]
  //   [13.1MB, +4.10MB) : Bf (100*20480 shorts)
  //   then W1f 32,768 B, W2f 4,096 B
  const size_t W_BYTES = (size_t)NB * NRODT * 2;     // 13,107,200
  unsigned short* wTbuf = (unsigned short*)d_ws;
  unsigned short* Bfb   = (unsigned short*)((char*)d_ws + W_BYTES);
  unsigned short* W1fb  = (unsigned short*)((char*)d_ws + W_BYTES + 4096000);
  unsigned short* W2fb  = (unsigned short*)((char*)d_ws + W_BYTES + 4096000 + 32768);

  k01_prep<<<1600 + NFOR + 2 + 3, 256, 0, stream>>>(
      x, w1, b1, perm, gn1w, gn1b, c2w, c2b, gn2w, gn2b, c3w, c3b,
      E, swr, fc1w, fc2w, wTbuf, Bfb, W1fb, W2fb, out);
  dim3 g3(NB / 128, NFOR);
  k3_mfma<<<g3, 256, 0, stream>>>(wTbuf, swr, Bfb, W1fb, W2fb,
                                  ln1w, ln1b, fc1b, ln2w, ln2b, fc2b, out);
}

// Round 8
// 209.483 us; speedup vs baseline: 1.0395x; 1.0395x over previous
//
#include <hip/hip_runtime.h>
#include <hip/hip_bf16.h>
#include <stdint.h>

#define NB 4096
#define NCOL 100
#define NCOND 64
#define NTOTAL 6400
#define NRODT 1600
#define NEST 160
#define NFOR 100
#define NHID 128
#define NCLS 10
#define GEPS 1e-5f

typedef __attribute__((ext_vector_type(8))) short short8;
typedef __attribute__((ext_vector_type(4))) float floatx4;

// round-half-up f32->bf16: 2 VALU ops; tie-only difference vs RNE
__device__ __forceinline__ unsigned f2bfu(float x) {
  union { float f; unsigned u; } v; v.f = x;
  return (v.u + 0x8000u) >> 16;
}
__device__ __forceinline__ float bf2f(unsigned short u) {
  union { unsigned u; float f; } v; v.u = ((unsigned)u) << 16;
  return v.f;
}

// all-reduce sum over the 16-lane DPP row -- VALU pipe, no LDS.
__device__ __forceinline__ float rowsum16(float v) {
  union { float f; int i; } a, t;
  a.f = v;
  t.i = __builtin_amdgcn_update_dpp(0, a.i, 0x128, 0xf, 0xf, true); a.f += t.f; // ror:8
  t.i = __builtin_amdgcn_update_dpp(0, a.i, 0x124, 0xf, 0xf, true); a.f += t.f; // ror:4
  t.i = __builtin_amdgcn_update_dpp(0, a.i, 0x122, 0xf, 0xf, true); a.f += t.f; // ror:2
  t.i = __builtin_amdgcn_update_dpp(0, a.i, 0x121, 0xf, 0xf, true); a.f += t.f; // ror:1
  return a.f;
}

// broadcast the value of each 16-lane group's leader (lane & 0x30) to the
// whole group: ds_swizzle BitMode, and_mask=0x10 (keeps bit4 within 32-half).
__device__ __forceinline__ float bcast16(float v) {
  union { float f; int i; } a; a.f = v;
  a.i = __builtin_amdgcn_ds_swizzle(a.i, 0x0010);
  return a.f;
}

// ---------------------------------------------------------------------------
// K01: merged prep kernel (single launch). Unchanged (proven).
//  blocks [0,1600)    : k1 -- ConditionGeneration+perm+phi_2 -> exp(w)^T bf16
//  blocks [1600,1702) : k0 -- fragment-pack Bf / W1f / W2f (identity k-map)
//  blocks [1702,1705) : zero d_out
// ---------------------------------------------------------------------------
__global__ __launch_bounds__(256) void k01_prep(
    const float* __restrict__ x, const float* __restrict__ w1,
    const float* __restrict__ b1, const int* __restrict__ perm,
    const float* __restrict__ gn1w, const float* __restrict__ gn1b,
    const float* __restrict__ c2w, const float* __restrict__ c2b,
    const float* __restrict__ gn2w, const float* __restrict__ gn2b,
    const float* __restrict__ c3w, const float* __restrict__ c3b,
    const float* __restrict__ E, const int* __restrict__ swr,
    const float* __restrict__ fc1w, const float* __restrict__ fc2w,
    unsigned short* __restrict__ wT,
    unsigned short* __restrict__ Bf, unsigned short* __restrict__ W1f,
    unsigned short* __restrict__ W2f, float* __restrict__ out)
{
  __shared__ float xl[64 * NCOL];          // k1 path only (25.6 KB)
  __shared__ int ridx[NEST];               // k0 path only
  const int tid = threadIdx.x;
  const int blk = blockIdx.x;

  if (blk < 1600) {
    // ---------------- k1: phi_2 logits -> exp -> bf16, transposed ----------
    const int b0 = (blk & 63) * 64;
    const int g  = (blk >> 6) * 64 + (tid >> 2);
    const int i4 = tid & 3;
    for (int i = tid; i < 64 * NCOL; i += 256)
      xl[i] = x[(size_t)b0 * NCOL + i];
    __syncthreads();

    const int4 p4 = *(const int4*)(perm + 4 * g);
    const int pv[4] = {p4.x, p4.y, p4.z, p4.w};
    float w1v[4], b1v[4];
    int pc[4];
#pragma unroll
    for (int i = 0; i < 4; i++) {
      unsigned p = (unsigned)pv[i];
      unsigned j = p / 100u;
      unsigned cc = p - j * 100u;
      pc[i] = (int)cc;
      w1v[i] = w1[cc * NCOND + j];
      b1v[i] = b1[cc * NCOND + j];
    }
    const float4 g1w = *(const float4*)(gn1w + 4 * g);
    const float4 g1b = *(const float4*)(gn1b + 4 * g);
    const float4 cw0 = *(const float4*)(c2w + 16 * g);
    const float4 cw1 = *(const float4*)(c2w + 16 * g + 4);
    const float4 cw2 = *(const float4*)(c2w + 16 * g + 8);
    const float4 cw3 = *(const float4*)(c2w + 16 * g + 12);
    const float4 cbv = *(const float4*)(c2b + 4 * g);
    const float4 g2w = *(const float4*)(gn2w + 4 * g);
    const float4 g2b = *(const float4*)(gn2b + 4 * g);
    const float4 c3v = *(const float4*)(c3w + 4 * g);
    const float c3bv = c3b[g];

    for (int k = 0; k < 4; k++) {
      float v4[4];
#pragma unroll
      for (int j = 0; j < 4; j++) {
        const int bb = k * 16 + i4 * 4 + j;
        float O[4];
#pragma unroll
        for (int i = 0; i < 4; i++) {
          float a = xl[bb * NCOL + pc[i]] * w1v[i] + b1v[i];
          O[i] = 1.0f / (1.0f + __expf(-a));
        }
        float mu = 0.25f * (O[0] + O[1] + O[2] + O[3]);
        float d[4], var = 0.f;
#pragma unroll
        for (int i = 0; i < 4; i++) { d[i] = O[i] - mu; var += d[i] * d[i]; }
        float rs = rsqrtf(0.25f * var + GEPS);
        float xn0 = d[0] * rs * g1w.x + g1b.x;
        float xn1 = d[1] * rs * g1w.y + g1b.y;
        float xn2 = d[2] * rs * g1w.z + g1b.z;
        float xn3 = d[3] * rs * g1w.w + g1b.w;
        float h[4];
        h[0] = xn0*cw0.x + xn1*cw1.x + xn2*cw2.x + xn3*cw3.x + cbv.x;
        h[1] = xn0*cw0.y + xn1*cw1.y + xn2*cw2.y + xn3*cw3.y + cbv.y;
        h[2] = xn0*cw0.z + xn1*cw1.z + xn2*cw2.z + xn3*cw3.z + cbv.z;
        h[3] = xn0*cw0.w + xn1*cw1.w + xn2*cw2.w + xn3*cw3.w + cbv.w;
#pragma unroll
        for (int i = 0; i < 4; i++) h[i] = fmaxf(h[i], 0.f);
        float mu2 = 0.25f * (h[0] + h[1] + h[2] + h[3]);
        float e[4], var2 = 0.f;
#pragma unroll
        for (int i = 0; i < 4; i++) { e[i] = h[i] - mu2; var2 += e[i] * e[i]; }
        float rs2 = rsqrtf(0.25f * var2 + GEPS);
        float hn0 = e[0] * rs2 * g2w.x + g2b.x;
        float hn1 = e[1] * rs2 * g2w.y + g2b.y;
        float hn2 = e[2] * rs2 * g2w.z + g2b.z;
        float hn3 = e[3] * rs2 * g2w.w + g2b.w;
        v4[j] = hn0*c3v.x + hn1*c3v.y + hn2*c3v.z + hn3*c3v.w + c3bv;
      }
      // store exp(logit): k3's softmax numerator, once per unique (g,b)
      uint2 pk;
      pk.x = f2bfu(__expf(v4[0])) | (f2bfu(__expf(v4[1])) << 16);
      pk.y = f2bfu(__expf(v4[2])) | (f2bfu(__expf(v4[3])) << 16);
      *(uint2*)(wT + (size_t)g * NB + b0 + k * 16 + i4 * 4) = pk;
    }
  } else if (blk < 1600 + NFOR) {
    // ---------------- k0: Bf fragment pack ----------------
    const int fblk = blk - 1600;
    if (tid < NEST) ridx[tid] = swr[fblk * NEST + tid];
    __syncthreads();
    for (int m = tid; m < 2560; m += 256) {        // m = (n*5+kc)*64 + lane
      int lane = m & 63, rest = m >> 6;
      int kc = rest % 5, n = rest / 5;
      int q = lane >> 4, c = lane & 15;
      int e0 = kc * 32 + q * 8;
      int h = n * 16 + c;
      union { unsigned short v[8]; uint4 u; } t;
#pragma unroll
      for (int j = 0; j < 8; j++)
        t.v[j] = (unsigned short)f2bfu(E[(size_t)ridx[e0 + j] * NHID + h]);
      *(uint4*)(Bf + (size_t)fblk * 20480 + (size_t)m * 8) = t.u;
    }
  } else if (blk == 1600 + NFOR) {
    // ---------------- k0: W1f (identity k-map) ----------------
    for (int m = tid; m < 2048; m += 256) {        // m = (n*4+kc)*64 + lane
      int lane = m & 63, rest = m >> 6;
      int kc = rest & 3, n = rest >> 2;
      int q = lane >> 4, c = lane & 15;
      int k0 = kc * 32 + q * 8;
      int o = n * 16 + c;
      union { unsigned short v[8]; uint4 u; } t;
#pragma unroll
      for (int j = 0; j < 8; j++)
        t.v[j] = (unsigned short)f2bfu(fc1w[(size_t)(k0 + j) * NHID + o]);
      *(uint4*)(W1f + (size_t)m * 8) = t.u;
    }
  } else if (blk == 1601 + NFOR) {
    // ---------------- k0: W2f (identity k-map) ----------------
    for (int m = tid; m < 256; m += 256) {         // m = kc*64 + lane
      int lane = m & 63, kc = m >> 6;
      int q = lane >> 4, c = lane & 15;
      int k0 = kc * 32 + q * 8;
      union { unsigned short v[8]; uint4 u; } t;
#pragma unroll
      for (int j = 0; j < 8; j++)
        t.v[j] = (unsigned short)f2bfu(c < NCLS ? fc2w[(size_t)(k0 + j) * NCLS + c] : 0.f);
      *(uint4*)(W2f + (size_t)m * 8) = t.u;
    }
  } else {
    // ---------------- zero d_out (3 blocks) ----------------
    const int z = blk - (1602 + NFOR);
    float4 zz = make_float4(0.f, 0.f, 0.f, 0.f);
    for (int i = z * 256 + tid; i < NB * NCLS / 4; i += 3 * 256)
      ((float4*)out)[i] = zz;
  }
}

// ---------------------------------------------------------------------------
// K3 (R25): R23 body + LDS 43008 -> 40960 B via SLOT ROTATION (not bit-XOR):
//  row = 20 slots of 16 B; physical slot p = (s+row)&15 for s<16,
//  p = 16+((s+row)&3) for s in 16..19. Read bank orbit (16 lanes, row=R+c):
//  b(t) = (16t + 4((s+t)&15)) mod 32 = (20t+4s) mod 32 -> full 8-group spread
//  (R24's 1-bit XOR only reached 4 groups -> 6M conflicts; and its
//  launch_bounds(256,4) VGPR cap 128 caused scratch spills).
//  Occupancy: keep bounds (256,3) -- allocator never squeezed (R23 used 80
//  VGPR) -- and let LDS drive it: 4 x 40960 = 163840 = exactly 160 KiB ->
//  4 blocks/CU when VGPR <= 128. Rotation uses LOCAL row (0..63); tile1 is
//  +20480 B, folded into the ds offset immediate -> one pointer set serves
//  both tiles and GEMM1/GEMM2/fc2 share rd[0..3].
//  Straight-line body, statically-indexed register arrays only (R18 lesson).
// ---------------------------------------------------------------------------
__global__ __launch_bounds__(256, 3) void k3_mfma(
    const unsigned short* __restrict__ wT,    // [1600][B] bf16 exp(logits)^T
    const int* __restrict__ swr,
    const unsigned short* __restrict__ Bf,    // [f][8][5][64][8]
    const unsigned short* __restrict__ W1f,   // [8][4][64][8]
    const unsigned short* __restrict__ W2f,   // [4][64][8]
    const float* __restrict__ ln1w, const float* __restrict__ ln1b,
    const float* __restrict__ fc1b,
    const float* __restrict__ ln2w, const float* __restrict__ ln2b,
    const float* __restrict__ fc2b,
    float* __restrict__ out)
{
  __shared__ unsigned short lsA[128 * 160];   // 40960 B: 4 blocks/CU exactly
  char* const lsb = (char*)lsA;
  #define T1B 20480                           // tile-1 byte offset (64*320)

  const int tid = threadIdx.x;
  // ---- XCD-chunked swizzle: id -> (bx, f) ----
  const int id  = blockIdx.y * 32 + blockIdx.x;   // linear dispatch id, [0,3200)
  const int xcd = id & 7;
  const int pos = id >> 3;                        // [0,400)
  const int f   = pos >> 2;                       // [0,100)
  const int b0  = (xcd * 4 + (pos & 3)) * 128;    // bx in [4*xcd, 4*xcd+4)
  const int lane = tid & 63;
  const int wv = __builtin_amdgcn_readfirstlane(tid >> 6);  // wave-uniform SGPR
  const int c = lane & 15, q = lane >> 4;

  // ---- gather phase: wave wv covers e in [40wv,40wv+40) for BOTH tiles ----
  // 2 chunks of 20 loads (R23 depth); repack into 5 slot-aligned uint4 per
  // tile, stored at rotated physical slots.
  {
    const unsigned short* wbase = wT + b0 + lane;
    const int* swf = swr + f * NEST + wv * 40;
    int idx[40];
#pragma unroll
    for (int e = 0; e < 40; e++) idx[e] = swf[e];

    // rotated byte addrs of this wave's 5 slots (s = 5wv+k), row = lane
    int sp[5];
#pragma unroll
    for (int k = 0; k < 5; k++) {
      int s = 5 * wv + k;                          // wave-uniform
      int p = (s < 16) ? ((s + lane) & 15) : (16 + ((s + lane) & 3));
      sp[k] = lane * 320 + p * 16;
    }

#define MKU(a, i) ((unsigned)(a)[i] | ((unsigned)(a)[i + 1] << 16))
    uint2 l0t0, l0t1;                              // shorts 16..19 carry-over
    {
      unsigned short u0[20], u1[20];
#pragma unroll
      for (int e = 0; e < 20; e++) {
        const unsigned short* p = wbase + (size_t)idx[e] * NB;
        u0[e] = p[0];
        u1[e] = p[64];
      }
      uint4 s0t0 = {MKU(u0,0), MKU(u0,2), MKU(u0,4), MKU(u0,6)};
      uint4 s1t0 = {MKU(u0,8), MKU(u0,10), MKU(u0,12), MKU(u0,14)};
      l0t0 = (uint2){MKU(u0,16), MKU(u0,18)};
      uint4 s0t1 = {MKU(u1,0), MKU(u1,2), MKU(u1,4), MKU(u1,6)};
      uint4 s1t1 = {MKU(u1,8), MKU(u1,10), MKU(u1,12), MKU(u1,14)};
      l0t1 = (uint2){MKU(u1,16), MKU(u1,18)};
      *(uint4*)(lsb + sp[0]) = s0t0;  *(uint4*)(lsb + T1B + sp[0]) = s0t1;
      *(uint4*)(lsb + sp[1]) = s1t0;  *(uint4*)(lsb + T1B + sp[1]) = s1t1;
    }
    {
      unsigned short u0[20], u1[20];
#pragma unroll
      for (int e = 0; e < 20; e++) {
        const unsigned short* p = wbase + (size_t)idx[20 + e] * NB;
        u0[e] = p[0];
        u1[e] = p[64];
      }
      uint4 s2t0 = {l0t0.x, l0t0.y, MKU(u0,0), MKU(u0,2)};
      uint4 s3t0 = {MKU(u0,4), MKU(u0,6), MKU(u0,8), MKU(u0,10)};
      uint4 s4t0 = {MKU(u0,12), MKU(u0,14), MKU(u0,16), MKU(u0,18)};
      uint4 s2t1 = {l0t1.x, l0t1.y, MKU(u1,0), MKU(u1,2)};
      uint4 s3t1 = {MKU(u1,4), MKU(u1,6), MKU(u1,8), MKU(u1,10)};
      uint4 s4t1 = {MKU(u1,12), MKU(u1,14), MKU(u1,16), MKU(u1,18)};
      *(uint4*)(lsb + sp[2]) = s2t0;  *(uint4*)(lsb + T1B + sp[2]) = s2t1;
      *(uint4*)(lsb + sp[3]) = s3t0;  *(uint4*)(lsb + T1B + sp[3]) = s3t1;
      *(uint4*)(lsb + sp[4]) = s4t0;  *(uint4*)(lsb + T1B + sp[4]) = s4t1;
    }
#undef MKU
  }

  // ---- prefetch GEMM1 kc=0 B-fragments (independent of gather/barrier) ----
  const unsigned short* bbase = Bf + (size_t)f * 20480 + lane * 8;
  short8 bp[8];
#pragma unroll
  for (int n = 0; n < 8; n++)
    bp[n] = *(const short8*)(bbase + n * 2560);

  __syncthreads();                     // the ONLY barrier

  // ---- A-fragment read addrs: slot s = kc*4+q of row r = wv*16+c ----
  // rd[kc] serves GEMM1 (kc 0..4), GEMM2 + fc2 (kc 0..3). Tile1 = +T1B.
  const int r = wv * 16 + c;
  int rd[5];
#pragma unroll
  for (int kc = 0; kc < 5; kc++) {
    int p = (kc < 4) ? (((kc * 4 + q) + r) & 15) : (16 + ((q + r) & 3));
    rd[kc] = r * 320 + p * 16;
  }

  // ---- GEMM1: (exp-ws)[128x160] @ Ep[160x128]; B loaded once per 2 tiles --
  //      + ones-column MFMA computing the softmax denominators
  const short onev = (c == 0) ? (short)0x3F80 : (short)0;  // bf16 1.0 in col 0
  short8 bones;
#pragma unroll
  for (int j = 0; j < 8; j++) bones[j] = onev;

  floatx4 acc0[8], acc1[8];
  floatx4 accs0 = (floatx4){0.f, 0.f, 0.f, 0.f};
  floatx4 accs1 = (floatx4){0.f, 0.f, 0.f, 0.f};
  __builtin_amdgcn_s_setprio(1);
  {
    short8 a0 = *(const short8*)(lsb + rd[0]);
    short8 a1 = *(const short8*)(lsb + T1B + rd[0]);
#pragma unroll
    for (int n = 0; n < 8; n++) {
      acc0[n] = __builtin_amdgcn_mfma_f32_16x16x32_bf16(a0, bp[n], (floatx4){0.f,0.f,0.f,0.f}, 0, 0, 0);
      acc1[n] = __builtin_amdgcn_mfma_f32_16x16x32_bf16(a1, bp[n], (floatx4){0.f,0.f,0.f,0.f}, 0, 0, 0);
    }
    accs0 = __builtin_amdgcn_mfma_f32_16x16x32_bf16(a0, bones, accs0, 0, 0, 0);
    accs1 = __builtin_amdgcn_mfma_f32_16x16x32_bf16(a1, bones, accs1, 0, 0, 0);
  }
#pragma unroll
  for (int kc = 1; kc < 5; kc++) {
    short8 a0 = *(const short8*)(lsb + rd[kc]);
    short8 a1 = *(const short8*)(lsb + T1B + rd[kc]);
#pragma unroll
    for (int n = 0; n < 8; n++) {
      short8 b = *(const short8*)(bbase + n * 2560 + kc * 512);
      acc0[n] = __builtin_amdgcn_mfma_f32_16x16x32_bf16(a0, b, acc0[n], 0, 0, 0);
      acc1[n] = __builtin_amdgcn_mfma_f32_16x16x32_bf16(a1, b, acc1[n], 0, 0, 0);
    }
    accs0 = __builtin_amdgcn_mfma_f32_16x16x32_bf16(a0, bones, accs0, 0, 0, 0);
    accs1 = __builtin_amdgcn_mfma_f32_16x16x32_bf16(a1, bones, accs1, 0, 0, 0);
  }
  __builtin_amdgcn_s_setprio(0);

  // ---- LN1 (both tiles): LN(x/s) == (x-mu)*rsqrt(var + eps*s^2) ----
  {
    float lw[8], lb[8];
#pragma unroll
    for (int n = 0; n < 8; n++) { lw[n] = ln1w[n * 16 + c]; lb[n] = ln1b[n * 16 + c]; }
#pragma unroll
    for (int rr = 0; rr < 4; rr++) {
      {
        float st = bcast16(accs0[rr]);         // denominator, row q*4+rr (t0)
        float s1 = 0.f, s2 = 0.f;
#pragma unroll
        for (int n = 0; n < 8; n++) { float v = acc0[n][rr]; s1 += v; s2 += v * v; }
        s1 = rowsum16(s1);
        s2 = rowsum16(s2);
        float mu = s1 * (1.f / 128.f);
        float var = fmaxf(s2 * (1.f / 128.f) - mu * mu, 0.f);
        float rs = rsqrtf(var + GEPS * st * st);
#pragma unroll
        for (int n = 0; n < 8; n++)
          acc0[n][rr] = (acc0[n][rr] - mu) * rs * lw[n] + lb[n];
      }
      {
        float st = bcast16(accs1[rr]);         // denominator, row q*4+rr (t1)
        float s1 = 0.f, s2 = 0.f;
#pragma unroll
        for (int n = 0; n < 8; n++) { float v = acc1[n][rr]; s1 += v; s2 += v * v; }
        s1 = rowsum16(s1);
        s2 = rowsum16(s2);
        float mu = s1 * (1.f / 128.f);
        float var = fmaxf(s2 * (1.f / 128.f) - mu * mu, 0.f);
        float rs = rsqrtf(var + GEPS * st * st);
#pragma unroll
        for (int n = 0; n < 8; n++)
          acc1[n][rr] = (acc1[n][rr] - mu) * rs * lw[n] + lb[n];
      }
    }
  }

  // ---- Fn -> lsA (A-layout bf16, wave-private rows; no barrier needed) ----
  // col n*16+c -> slot s = 2n+(c>>3) (domain A), within-slot (c&7)*2.
#pragma unroll
  for (int rr = 0; rr < 4; rr++) {
    const int rw = wv * 16 + q * 4 + rr;
    const int wb = rw * 320 + (c & 7) * 2;
    const int b0r = (c >> 3) + rw;
#pragma unroll
    for (int n = 0; n < 8; n++) {
      const int ad = wb + ((b0r + 2 * n) & 15) * 16;
      *(unsigned short*)(lsb + ad)       = (unsigned short)f2bfu(acc0[n][rr]);
      *(unsigned short*)(lsb + T1B + ad) = (unsigned short)f2bfu(acc1[n][rr]);
    }
  }

  // ---- GEMM2: H = Fn[128x128] @ fc1w[128x128]; W1f loaded once per 2 tiles -
  {
    short8 a00 = *(const short8*)(lsb + rd[0]);
    short8 a01 = *(const short8*)(lsb + rd[1]);
    short8 a02 = *(const short8*)(lsb + rd[2]);
    short8 a03 = *(const short8*)(lsb + rd[3]);
    short8 a10 = *(const short8*)(lsb + T1B + rd[0]);
    short8 a11 = *(const short8*)(lsb + T1B + rd[1]);
    short8 a12 = *(const short8*)(lsb + T1B + rd[2]);
    short8 a13 = *(const short8*)(lsb + T1B + rd[3]);
    const unsigned short* w1p = W1f + lane * 8;
    __builtin_amdgcn_s_setprio(1);
#pragma unroll
    for (int n = 0; n < 8; n++) {
      const unsigned short* wp = w1p + n * 2048;
      short8 b0v = *(const short8*)(wp);
      short8 b1v = *(const short8*)(wp + 512);
      short8 b2v = *(const short8*)(wp + 1024);
      short8 b3v = *(const short8*)(wp + 1536);
      floatx4 t0 = __builtin_amdgcn_mfma_f32_16x16x32_bf16(a00, b0v, (floatx4){0.f,0.f,0.f,0.f}, 0, 0, 0);
      t0 = __builtin_amdgcn_mfma_f32_16x16x32_bf16(a01, b1v, t0, 0, 0, 0);
      t0 = __builtin_amdgcn_mfma_f32_16x16x32_bf16(a02, b2v, t0, 0, 0, 0);
      t0 = __builtin_amdgcn_mfma_f32_16x16x32_bf16(a03, b3v, t0, 0, 0, 0);
      floatx4 t1 = __builtin_amdgcn_mfma_f32_16x16x32_bf16(a10, b0v, (floatx4){0.f,0.f,0.f,0.f}, 0, 0, 0);
      t1 = __builtin_amdgcn_mfma_f32_16x16x32_bf16(a11, b1v, t1, 0, 0, 0);
      t1 = __builtin_amdgcn_mfma_f32_16x16x32_bf16(a12, b2v, t1, 0, 0, 0);
      t1 = __builtin_amdgcn_mfma_f32_16x16x32_bf16(a13, b3v, t1, 0, 0, 0);
      acc0[n] = t0;
      acc1[n] = t1;
    }
    __builtin_amdgcn_s_setprio(0);
  }

  // ---- bias + ReLU + LN2 (both tiles, DPP row-reduce) ----
  {
    float fb[8], lw[8], lb[8];
#pragma unroll
    for (int n = 0; n < 8; n++) {
      fb[n] = fc1b[n * 16 + c];
      lw[n] = ln2w[n * 16 + c]; lb[n] = ln2b[n * 16 + c];
    }
#pragma unroll
    for (int rr = 0; rr < 4; rr++) {
      {
#pragma unroll
        for (int n = 0; n < 8; n++) acc0[n][rr] = fmaxf(acc0[n][rr] + fb[n], 0.f);
        float s1 = 0.f, s2 = 0.f;
#pragma unroll
        for (int n = 0; n < 8; n++) { float v = acc0[n][rr]; s1 += v; s2 += v * v; }
        s1 = rowsum16(s1);
        s2 = rowsum16(s2);
        float mu = s1 * (1.f / 128.f);
        float var = fmaxf(s2 * (1.f / 128.f) - mu * mu, 0.f);
        float rs = rsqrtf(var + GEPS);
#pragma unroll
        for (int n = 0; n < 8; n++)
          acc0[n][rr] = (acc0[n][rr] - mu) * rs * lw[n] + lb[n];
      }
      {
#pragma unroll
        for (int n = 0; n < 8; n++) acc1[n][rr] = fmaxf(acc1[n][rr] + fb[n], 0.f);
        float s1 = 0.f, s2 = 0.f;
#pragma unroll
        for (int n = 0; n < 8; n++) { float v = acc1[n][rr]; s1 += v; s2 += v * v; }
        s1 = rowsum16(s1);
        s2 = rowsum16(s2);
        float mu = s1 * (1.f / 128.f);
        float var = fmaxf(s2 * (1.f / 128.f) - mu * mu, 0.f);
        float rs = rsqrtf(var + GEPS);
#pragma unroll
        for (int n = 0; n < 8; n++)
          acc1[n][rr] = (acc1[n][rr] - mu) * rs * lw[n] + lb[n];
      }
    }
  }

  // ---- H2 -> lsA (A-layout, wave-private rows; no barrier) ----
#pragma unroll
  for (int rr = 0; rr < 4; rr++) {
    const int rw = wv * 16 + q * 4 + rr;
    const int wb = rw * 320 + (c & 7) * 2;
    const int b0r = (c >> 3) + rw;
#pragma unroll
    for (int n = 0; n < 8; n++) {
      const int ad = wb + ((b0r + 2 * n) & 15) * 16;
      *(unsigned short*)(lsb + ad)       = (unsigned short)f2bfu(acc0[n][rr]);
      *(unsigned short*)(lsb + T1B + ad) = (unsigned short)f2bfu(acc1[n][rr]);
    }
  }

  // ---- fc2 (16-col padded tile), W2f loaded once per 2 tiles ----
  floatx4 o40 = (floatx4){0.f, 0.f, 0.f, 0.f};
  floatx4 o41 = (floatx4){0.f, 0.f, 0.f, 0.f};
#pragma unroll
  for (int kc = 0; kc < 4; kc++) {
    short8 a0 = *(const short8*)(lsb + rd[kc]);
    short8 a1 = *(const short8*)(lsb + T1B + rd[kc]);
    short8 b = *(const short8*)(W2f + kc * 512 + lane * 8);
    o40 = __builtin_amdgcn_mfma_f32_16x16x32_bf16(a0, b, o40, 0, 0, 0);
    o41 = __builtin_amdgcn_mfma_f32_16x16x32_bf16(a1, b, o41, 0, 0, 0);
  }
  if (c < NCLS) {
    float bias = fc2b[c];
#pragma unroll
    for (int rr = 0; rr < 4; rr++) {
      atomicAdd(out + (size_t)(b0 + wv * 16 + q * 4 + rr) * NCLS + c,
                (o40[rr] + bias) * 0.01f);
      atomicAdd(out + (size_t)(b0 + 64 + wv * 16 + q * 4 + rr) * NCLS + c,
                (o41[rr] + bias) * 0.01f);
    }
  }
  #undef T1B
}

// ---------------------------------------------------------------------------
extern "C" void kernel_launch(void* const* d_in, const int* in_sizes, int n_in,
                              void* d_out, int out_size, void* d_ws, size_t ws_size,
                              hipStream_t stream)
{
  (void)in_sizes; (void)n_in; (void)ws_size; (void)out_size;
  const float* x    = (const float*)d_in[0];
  const float* w1   = (const float*)d_in[1];
  const float* b1   = (const float*)d_in[2];
  const int*   perm = (const int*)d_in[3];
  const float* gn1w = (const float*)d_in[4];
  const float* gn1b = (const float*)d_in[5];
  const float* c2w  = (const float*)d_in[6];
  const float* c2b  = (const float*)d_in[7];
  const float* gn2w = (const float*)d_in[8];
  const float* gn2b = (const float*)d_in[9];
  const float* c3w  = (const float*)d_in[10];
  const float* c3b  = (const float*)d_in[11];
  const int*   swr  = (const int*)d_in[12];
  const float* E    = (const float*)d_in[13];
  const float* ln1w = (const float*)d_in[14];
  const float* ln1b = (const float*)d_in[15];
  const float* fc1w = (const float*)d_in[16];
  const float* fc1b = (const float*)d_in[17];
  const float* ln2w = (const float*)d_in[18];
  const float* ln2b = (const float*)d_in[19];
  const float* fc2w = (const float*)d_in[20];
  const float* fc2b = (const float*)d_in[21];
  float* out = (float*)d_out;

  // workspace layout:
  //   [0, 13.1MB)       : wT exp-logits bf16 [1600][B]
  //   [13.1MB, +4.10MB) : Bf (100*20480 shorts)
  //   then W1f 32,768 B, W2f 4,096 B
  const size_t W_BYTES = (size_t)NB * NRODT * 2;     // 13,107,200
  unsigned short* wTbuf = (unsigned short*)d_ws;
  unsigned short* Bfb   = (unsigned short*)((char*)d_ws + W_BYTES);
  unsigned short* W1fb  = (unsigned short*)((char*)d_ws + W_BYTES + 4096000);
  unsigned short* W2fb  = (unsigned short*)((char*)d_ws + W_BYTES + 4096000 + 32768);

  k01_prep<<<1600 + NFOR + 2 + 3, 256, 0, stream>>>(
      x, w1, b1, perm, gn1w, gn1b, c2w, c2b, gn2w, gn2b, c3w, c3b,
      E, swr, fc1w, fc2w, wTbuf, Bfb, W1fb, W2fb, out);
  dim3 g3(NB / 128, NFOR);
  k3_mfma<<<g3, 256, 0, stream>>>(wTbuf, swr, Bfb, W1fb, W2fb,
                                  ln1w, ln1b, fc1b, ln2w, ln2b, fc2b, out);
}

// Round 9
// 205.473 us; speedup vs baseline: 1.0598x; 1.0195x over previous
//
#include <hip/hip_runtime.h>
#include <hip/hip_bf16.h>
#include <stdint.h>

#define NB 4096
#define NCOL 100
#define NCOND 64
#define NTOTAL 6400
#define NRODT 1600
#define NEST 160
#define NFOR 100
#define NHID 128
#define NCLS 10
#define GEPS 1e-5f

typedef __attribute__((ext_vector_type(8))) short short8;
typedef __attribute__((ext_vector_type(4))) float floatx4;

// round-half-up f32->bf16: 2 VALU ops; tie-only difference vs RNE
__device__ __forceinline__ unsigned f2bfu(float x) {
  union { float f; unsigned u; } v; v.f = x;
  return (v.u + 0x8000u) >> 16;
}
__device__ __forceinline__ float bf2f(unsigned short u) {
  union { unsigned u; float f; } v; v.u = ((unsigned)u) << 16;
  return v.f;
}

// all-reduce sum over the 16-lane DPP row -- VALU pipe, no LDS.
__device__ __forceinline__ float rowsum16(float v) {
  union { float f; int i; } a, t;
  a.f = v;
  t.i = __builtin_amdgcn_update_dpp(0, a.i, 0x128, 0xf, 0xf, true); a.f += t.f; // ror:8
  t.i = __builtin_amdgcn_update_dpp(0, a.i, 0x124, 0xf, 0xf, true); a.f += t.f; // ror:4
  t.i = __builtin_amdgcn_update_dpp(0, a.i, 0x122, 0xf, 0xf, true); a.f += t.f; // ror:2
  t.i = __builtin_amdgcn_update_dpp(0, a.i, 0x121, 0xf, 0xf, true); a.f += t.f; // ror:1
  return a.f;
}

// broadcast the value of each 16-lane group's leader (lane & 0x30) to the
// whole group: ds_swizzle BitMode, and_mask=0x10 (keeps bit4 within 32-half).
__device__ __forceinline__ float bcast16(float v) {
  union { float f; int i; } a; a.f = v;
  a.i = __builtin_amdgcn_ds_swizzle(a.i, 0x0010);
  return a.f;
}

// ---------------------------------------------------------------------------
// K01: merged prep kernel (single launch). Unchanged (proven).
//  blocks [0,1600)    : k1 -- ConditionGeneration+perm+phi_2 -> exp(w)^T bf16
//  blocks [1600,1702) : k0 -- fragment-pack Bf / W1f / W2f (identity k-map)
//  blocks [1702,1705) : zero d_out
// ---------------------------------------------------------------------------
__global__ __launch_bounds__(256) void k01_prep(
    const float* __restrict__ x, const float* __restrict__ w1,
    const float* __restrict__ b1, const int* __restrict__ perm,
    const float* __restrict__ gn1w, const float* __restrict__ gn1b,
    const float* __restrict__ c2w, const float* __restrict__ c2b,
    const float* __restrict__ gn2w, const float* __restrict__ gn2b,
    const float* __restrict__ c3w, const float* __restrict__ c3b,
    const float* __restrict__ E, const int* __restrict__ swr,
    const float* __restrict__ fc1w, const float* __restrict__ fc2w,
    unsigned short* __restrict__ wT,
    unsigned short* __restrict__ Bf, unsigned short* __restrict__ W1f,
    unsigned short* __restrict__ W2f, float* __restrict__ out)
{
  __shared__ float xl[64 * NCOL];          // k1 path only (25.6 KB)
  __shared__ int ridx[NEST];               // k0 path only
  const int tid = threadIdx.x;
  const int blk = blockIdx.x;

  if (blk < 1600) {
    // ---------------- k1: phi_2 logits -> exp -> bf16, transposed ----------
    const int b0 = (blk & 63) * 64;
    const int g  = (blk >> 6) * 64 + (tid >> 2);
    const int i4 = tid & 3;
    for (int i = tid; i < 64 * NCOL; i += 256)
      xl[i] = x[(size_t)b0 * NCOL + i];
    __syncthreads();

    const int4 p4 = *(const int4*)(perm + 4 * g);
    const int pv[4] = {p4.x, p4.y, p4.z, p4.w};
    float w1v[4], b1v[4];
    int pc[4];
#pragma unroll
    for (int i = 0; i < 4; i++) {
      unsigned p = (unsigned)pv[i];
      unsigned j = p / 100u;
      unsigned cc = p - j * 100u;
      pc[i] = (int)cc;
      w1v[i] = w1[cc * NCOND + j];
      b1v[i] = b1[cc * NCOND + j];
    }
    const float4 g1w = *(const float4*)(gn1w + 4 * g);
    const float4 g1b = *(const float4*)(gn1b + 4 * g);
    const float4 cw0 = *(const float4*)(c2w + 16 * g);
    const float4 cw1 = *(const float4*)(c2w + 16 * g + 4);
    const float4 cw2 = *(const float4*)(c2w + 16 * g + 8);
    const float4 cw3 = *(const float4*)(c2w + 16 * g + 12);
    const float4 cbv = *(const float4*)(c2b + 4 * g);
    const float4 g2w = *(const float4*)(gn2w + 4 * g);
    const float4 g2b = *(const float4*)(gn2b + 4 * g);
    const float4 c3v = *(const float4*)(c3w + 4 * g);
    const float c3bv = c3b[g];

    for (int k = 0; k < 4; k++) {
      float v4[4];
#pragma unroll
      for (int j = 0; j < 4; j++) {
        const int bb = k * 16 + i4 * 4 + j;
        float O[4];
#pragma unroll
        for (int i = 0; i < 4; i++) {
          float a = xl[bb * NCOL + pc[i]] * w1v[i] + b1v[i];
          O[i] = 1.0f / (1.0f + __expf(-a));
        }
        float mu = 0.25f * (O[0] + O[1] + O[2] + O[3]);
        float d[4], var = 0.f;
#pragma unroll
        for (int i = 0; i < 4; i++) { d[i] = O[i] - mu; var += d[i] * d[i]; }
        float rs = rsqrtf(0.25f * var + GEPS);
        float xn0 = d[0] * rs * g1w.x + g1b.x;
        float xn1 = d[1] * rs * g1w.y + g1b.y;
        float xn2 = d[2] * rs * g1w.z + g1b.z;
        float xn3 = d[3] * rs * g1w.w + g1b.w;
        float h[4];
        h[0] = xn0*cw0.x + xn1*cw1.x + xn2*cw2.x + xn3*cw3.x + cbv.x;
        h[1] = xn0*cw0.y + xn1*cw1.y + xn2*cw2.y + xn3*cw3.y + cbv.y;
        h[2] = xn0*cw0.z + xn1*cw1.z + xn2*cw2.z + xn3*cw3.z + cbv.z;
        h[3] = xn0*cw0.w + xn1*cw1.w + xn2*cw2.w + xn3*cw3.w + cbv.w;
#pragma unroll
        for (int i = 0; i < 4; i++) h[i] = fmaxf(h[i], 0.f);
        float mu2 = 0.25f * (h[0] + h[1] + h[2] + h[3]);
        float e[4], var2 = 0.f;
#pragma unroll
        for (int i = 0; i < 4; i++) { e[i] = h[i] - mu2; var2 += e[i] * e[i]; }
        float rs2 = rsqrtf(0.25f * var2 + GEPS);
        float hn0 = e[0] * rs2 * g2w.x + g2b.x;
        float hn1 = e[1] * rs2 * g2w.y + g2b.y;
        float hn2 = e[2] * rs2 * g2w.z + g2b.z;
        float hn3 = e[3] * rs2 * g2w.w + g2b.w;
        v4[j] = hn0*c3v.x + hn1*c3v.y + hn2*c3v.z + hn3*c3v.w + c3bv;
      }
      // store exp(logit): k3's softmax numerator, once per unique (g,b)
      uint2 pk;
      pk.x = f2bfu(__expf(v4[0])) | (f2bfu(__expf(v4[1])) << 16);
      pk.y = f2bfu(__expf(v4[2])) | (f2bfu(__expf(v4[3])) << 16);
      *(uint2*)(wT + (size_t)g * NB + b0 + k * 16 + i4 * 4) = pk;
    }
  } else if (blk < 1600 + NFOR) {
    // ---------------- k0: Bf fragment pack ----------------
    const int fblk = blk - 1600;
    if (tid < NEST) ridx[tid] = swr[fblk * NEST + tid];
    __syncthreads();
    for (int m = tid; m < 2560; m += 256) {        // m = (n*5+kc)*64 + lane
      int lane = m & 63, rest = m >> 6;
      int kc = rest % 5, n = rest / 5;
      int q = lane >> 4, c = lane & 15;
      int e0 = kc * 32 + q * 8;
      int h = n * 16 + c;
      union { unsigned short v[8]; uint4 u; } t;
#pragma unroll
      for (int j = 0; j < 8; j++)
        t.v[j] = (unsigned short)f2bfu(E[(size_t)ridx[e0 + j] * NHID + h]);
      *(uint4*)(Bf + (size_t)fblk * 20480 + (size_t)m * 8) = t.u;
    }
  } else if (blk == 1600 + NFOR) {
    // ---------------- k0: W1f (identity k-map) ----------------
    for (int m = tid; m < 2048; m += 256) {        // m = (n*4+kc)*64 + lane
      int lane = m & 63, rest = m >> 6;
      int kc = rest & 3, n = rest >> 2;
      int q = lane >> 4, c = lane & 15;
      int k0 = kc * 32 + q * 8;
      int o = n * 16 + c;
      union { unsigned short v[8]; uint4 u; } t;
#pragma unroll
      for (int j = 0; j < 8; j++)
        t.v[j] = (unsigned short)f2bfu(fc1w[(size_t)(k0 + j) * NHID + o]);
      *(uint4*)(W1f + (size_t)m * 8) = t.u;
    }
  } else if (blk == 1601 + NFOR) {
    // ---------------- k0: W2f (identity k-map) ----------------
    for (int m = tid; m < 256; m += 256) {         // m = kc*64 + lane
      int lane = m & 63, kc = m >> 6;
      int q = lane >> 4, c = lane & 15;
      int k0 = kc * 32 + q * 8;
      union { unsigned short v[8]; uint4 u; } t;
#pragma unroll
      for (int j = 0; j < 8; j++)
        t.v[j] = (unsigned short)f2bfu(c < NCLS ? fc2w[(size_t)(k0 + j) * NCLS + c] : 0.f);
      *(uint4*)(W2f + (size_t)m * 8) = t.u;
    }
  } else {
    // ---------------- zero d_out (3 blocks) ----------------
    const int z = blk - (1602 + NFOR);
    float4 zz = make_float4(0.f, 0.f, 0.f, 0.f);
    for (int i = z * 256 + tid; i < NB * NCLS / 4; i += 3 * 256)
      ((float4*)out)[i] = zz;
  }
}

// ---------------------------------------------------------------------------
// K3 (R26): R23 body (proven best: 336-stride LDS, 3 blocks/CU, ones-column
//  denominator, XCD swizzle, setprio) + DWORD-PAIR GATHER:
//  lane l loads ONE dword wT[e][b0+2l] covering b-pair (2l,2l+1) -- both
//  output tiles in 40 loads/wave instead of 80 2-byte loads. Lo/hi split
//  lands in rows 2l / 2l+1 (contiguous, rp1 = rp0+168 shorts). Halves the
//  gather's VMEM instruction count (R21 precedent: VMEM-count cuts pay in
//  this contention-bound regime). Same bytes, same downstream layout.
//  R24/R25 lesson: 4-blocks-via-40KB-LDS does NOT materialize (160KiB can't
//  be packed 100%) -- stay at 43008 B / 3 blocks, launch_bounds(256,3).
//  Straight-line body, statically-indexed register arrays only (R18 lesson).
// ---------------------------------------------------------------------------
__global__ __launch_bounds__(256, 3) void k3_mfma(
    const unsigned short* __restrict__ wT,    // [1600][B] bf16 exp(logits)^T
    const int* __restrict__ swr,
    const unsigned short* __restrict__ Bf,    // [f][8][5][64][8]
    const unsigned short* __restrict__ W1f,   // [8][4][64][8]
    const unsigned short* __restrict__ W2f,   // [4][64][8]
    const float* __restrict__ ln1w, const float* __restrict__ ln1b,
    const float* __restrict__ fc1b,
    const float* __restrict__ ln2w, const float* __restrict__ ln2b,
    const float* __restrict__ fc2b,
    float* __restrict__ out)
{
  __shared__ unsigned short lsA[128 * 168];   // 43008 B (rows 0-63 t0, 64-127 t1)

  const int tid = threadIdx.x;
  // ---- XCD-chunked swizzle: id -> (bx, f) ----
  const int id  = blockIdx.y * 32 + blockIdx.x;   // linear dispatch id, [0,3200)
  const int xcd = id & 7;
  const int pos = id >> 3;                        // [0,400)
  const int f   = pos >> 2;                       // [0,100)
  const int b0  = (xcd * 4 + (pos & 3)) * 128;    // bx in [4*xcd, 4*xcd+4)
  const int lane = tid & 63;
  const int wv = __builtin_amdgcn_readfirstlane(tid >> 6);  // wave-uniform SGPR
  const int c = lane & 15, q = lane >> 4;

  // ---- gather: wave wv covers e in [40wv,40wv+40); dword-pair loads ----
  // lane l reads wT[e][b0+2l .. b0+2l+1] as one dword (rows 2l, 2l+1 of the
  // combined 128-row tile; rows 64-127 ARE tile1 in this layout).
  {
    const int* swf = swr + f * NEST + wv * 40;    // wave-uniform -> s_load
    int idx[40];
#pragma unroll
    for (int e = 0; e < 40; e++) idx[e] = swf[e];

    const unsigned* wb32 = (const unsigned*)wT + (b0 >> 1) + lane;
    unsigned d[40];
#pragma unroll
    for (int e = 0; e < 40; e++)
      d[e] = wb32[(size_t)idx[e] * (NB / 2)];     // 40 loads in flight

    unsigned short* rp0 = lsA + (2 * lane) * 168 + wv * 40;   // row 2l
    unsigned short* rp1 = rp0 + 168;                          // row 2l+1

#define PKLO(a, b) (((a) & 0xFFFFu) | ((b) << 16))
#define PKHI(a, b) (((a) >> 16) | ((b) & 0xFFFF0000u))
#pragma unroll
    for (int k = 0; k < 5; k++) {
      uint4 lo = {PKLO(d[8*k+0], d[8*k+1]), PKLO(d[8*k+2], d[8*k+3]),
                  PKLO(d[8*k+4], d[8*k+5]), PKLO(d[8*k+6], d[8*k+7])};
      uint4 hi = {PKHI(d[8*k+0], d[8*k+1]), PKHI(d[8*k+2], d[8*k+3]),
                  PKHI(d[8*k+4], d[8*k+5]), PKHI(d[8*k+6], d[8*k+7])};
      *(uint4*)(rp0 + k * 8) = lo;
      *(uint4*)(rp1 + k * 8) = hi;
    }
#undef PKLO
#undef PKHI
  }

  // ---- prefetch GEMM1 kc=0 B-fragments (independent of gather/barrier) ----
  const unsigned short* bbase = Bf + (size_t)f * 20480 + lane * 8;
  short8 bp[8];
#pragma unroll
  for (int n = 0; n < 8; n++)
    bp[n] = *(const short8*)(bbase + n * 2560);

  __syncthreads();                     // the ONLY barrier

  // ---- GEMM1: (exp-ws)[128x160] @ Ep[160x128]; B loaded once per 2 tiles --
  //      + ones-column MFMA computing the softmax denominators
  const unsigned short* pa0 = lsA + (wv * 16 + c) * 168 + q * 8;
  const unsigned short* pa1 = pa0 + 64 * 168;
  const short onev = (c == 0) ? (short)0x3F80 : (short)0;  // bf16 1.0 in col 0
  short8 bones;
#pragma unroll
  for (int j = 0; j < 8; j++) bones[j] = onev;

  floatx4 acc0[8], acc1[8];
  floatx4 accs0 = (floatx4){0.f, 0.f, 0.f, 0.f};
  floatx4 accs1 = (floatx4){0.f, 0.f, 0.f, 0.f};
  __builtin_amdgcn_s_setprio(1);
  {
    short8 a0 = *(const short8*)(pa0);
    short8 a1 = *(const short8*)(pa1);
#pragma unroll
    for (int n = 0; n < 8; n++) {
      acc0[n] = __builtin_amdgcn_mfma_f32_16x16x32_bf16(a0, bp[n], (floatx4){0.f,0.f,0.f,0.f}, 0, 0, 0);
      acc1[n] = __builtin_amdgcn_mfma_f32_16x16x32_bf16(a1, bp[n], (floatx4){0.f,0.f,0.f,0.f}, 0, 0, 0);
    }
    accs0 = __builtin_amdgcn_mfma_f32_16x16x32_bf16(a0, bones, accs0, 0, 0, 0);
    accs1 = __builtin_amdgcn_mfma_f32_16x16x32_bf16(a1, bones, accs1, 0, 0, 0);
  }
#pragma unroll
  for (int kc = 1; kc < 5; kc++) {
    short8 a0 = *(const short8*)(pa0 + kc * 32);
    short8 a1 = *(const short8*)(pa1 + kc * 32);
#pragma unroll
    for (int n = 0; n < 8; n++) {
      short8 b = *(const short8*)(bbase + n * 2560 + kc * 512);
      acc0[n] = __builtin_amdgcn_mfma_f32_16x16x32_bf16(a0, b, acc0[n], 0, 0, 0);
      acc1[n] = __builtin_amdgcn_mfma_f32_16x16x32_bf16(a1, b, acc1[n], 0, 0, 0);
    }
    accs0 = __builtin_amdgcn_mfma_f32_16x16x32_bf16(a0, bones, accs0, 0, 0, 0);
    accs1 = __builtin_amdgcn_mfma_f32_16x16x32_bf16(a1, bones, accs1, 0, 0, 0);
  }
  __builtin_amdgcn_s_setprio(0);

  // ---- LN1 (both tiles): LN(x/s) == (x-mu)*rsqrt(var + eps*s^2) ----
  {
    float lw[8], lb[8];
#pragma unroll
    for (int n = 0; n < 8; n++) { lw[n] = ln1w[n * 16 + c]; lb[n] = ln1b[n * 16 + c]; }
#pragma unroll
    for (int rr = 0; rr < 4; rr++) {
      {
        float st = bcast16(accs0[rr]);         // denominator, row q*4+rr (t0)
        float s1 = 0.f, s2 = 0.f;
#pragma unroll
        for (int n = 0; n < 8; n++) { float v = acc0[n][rr]; s1 += v; s2 += v * v; }
        s1 = rowsum16(s1);
        s2 = rowsum16(s2);
        float mu = s1 * (1.f / 128.f);
        float var = fmaxf(s2 * (1.f / 128.f) - mu * mu, 0.f);
        float rs = rsqrtf(var + GEPS * st * st);
#pragma unroll
        for (int n = 0; n < 8; n++)
          acc0[n][rr] = (acc0[n][rr] - mu) * rs * lw[n] + lb[n];
      }
      {
        float st = bcast16(accs1[rr]);         // denominator, row q*4+rr (t1)
        float s1 = 0.f, s2 = 0.f;
#pragma unroll
        for (int n = 0; n < 8; n++) { float v = acc1[n][rr]; s1 += v; s2 += v * v; }
        s1 = rowsum16(s1);
        s2 = rowsum16(s2);
        float mu = s1 * (1.f / 128.f);
        float var = fmaxf(s2 * (1.f / 128.f) - mu * mu, 0.f);
        float rs = rsqrtf(var + GEPS * st * st);
#pragma unroll
        for (int n = 0; n < 8; n++)
          acc1[n][rr] = (acc1[n][rr] - mu) * rs * lw[n] + lb[n];
      }
    }
  }

  // ---- Fn -> lsA (A-layout bf16, wave-private rows; no barrier needed) ----
#pragma unroll
  for (int rr = 0; rr < 4; rr++)
#pragma unroll
    for (int n = 0; n < 8; n++) {
      lsA[(wv * 16 + q * 4 + rr) * 168 + n * 16 + c] =
          (unsigned short)f2bfu(acc0[n][rr]);
      lsA[(64 + wv * 16 + q * 4 + rr) * 168 + n * 16 + c] =
          (unsigned short)f2bfu(acc1[n][rr]);
    }

  // ---- GEMM2: H = Fn[128x128] @ fc1w[128x128]; W1f loaded once per 2 tiles -
  {
    short8 a00 = *(const short8*)(pa0);
    short8 a01 = *(const short8*)(pa0 + 32);
    short8 a02 = *(const short8*)(pa0 + 64);
    short8 a03 = *(const short8*)(pa0 + 96);
    short8 a10 = *(const short8*)(pa1);
    short8 a11 = *(const short8*)(pa1 + 32);
    short8 a12 = *(const short8*)(pa1 + 64);
    short8 a13 = *(const short8*)(pa1 + 96);
    const unsigned short* w1p = W1f + lane * 8;
    __builtin_amdgcn_s_setprio(1);
#pragma unroll
    for (int n = 0; n < 8; n++) {
      const unsigned short* wp = w1p + n * 2048;
      short8 b0v = *(const short8*)(wp);
      short8 b1v = *(const short8*)(wp + 512);
      short8 b2v = *(const short8*)(wp + 1024);
      short8 b3v = *(const short8*)(wp + 1536);
      floatx4 t0 = __builtin_amdgcn_mfma_f32_16x16x32_bf16(a00, b0v, (floatx4){0.f,0.f,0.f,0.f}, 0, 0, 0);
      t0 = __builtin_amdgcn_mfma_f32_16x16x32_bf16(a01, b1v, t0, 0, 0, 0);
      t0 = __builtin_amdgcn_mfma_f32_16x16x32_bf16(a02, b2v, t0, 0, 0, 0);
      t0 = __builtin_amdgcn_mfma_f32_16x16x32_bf16(a03, b3v, t0, 0, 0, 0);
      floatx4 t1 = __builtin_amdgcn_mfma_f32_16x16x32_bf16(a10, b0v, (floatx4){0.f,0.f,0.f,0.f}, 0, 0, 0);
      t1 = __builtin_amdgcn_mfma_f32_16x16x32_bf16(a11, b1v, t1, 0, 0, 0);
      t1 = __builtin_amdgcn_mfma_f32_16x16x32_bf16(a12, b2v, t1, 0, 0, 0);
      t1 = __builtin_amdgcn_mfma_f32_16x16x32_bf16(a13, b3v, t1, 0, 0, 0);
      acc0[n] = t0;
      acc1[n] = t1;
    }
    __builtin_amdgcn_s_setprio(0);
  }

  // ---- bias + ReLU + LN2 (both tiles, DPP row-reduce) ----
  {
    float fb[8], lw[8], lb[8];
#pragma unroll
    for (int n = 0; n < 8; n++) {
      fb[n] = fc1b[n * 16 + c];
      lw[n] = ln2w[n * 16 + c]; lb[n] = ln2b[n * 16 + c];
    }
#pragma unroll
    for (int rr = 0; rr < 4; rr++) {
      {
#pragma unroll
        for (int n = 0; n < 8; n++) acc0[n][rr] = fmaxf(acc0[n][rr] + fb[n], 0.f);
        float s1 = 0.f, s2 = 0.f;
#pragma unroll
        for (int n = 0; n < 8; n++) { float v = acc0[n][rr]; s1 += v; s2 += v * v; }
        s1 = rowsum16(s1);
        s2 = rowsum16(s2);
        float mu = s1 * (1.f / 128.f);
        float var = fmaxf(s2 * (1.f / 128.f) - mu * mu, 0.f);
        float rs = rsqrtf(var + GEPS);
#pragma unroll
        for (int n = 0; n < 8; n++)
          acc0[n][rr] = (acc0[n][rr] - mu) * rs * lw[n] + lb[n];
      }
      {
#pragma unroll
        for (int n = 0; n < 8; n++) acc1[n][rr] = fmaxf(acc1[n][rr] + fb[n], 0.f);
        float s1 = 0.f, s2 = 0.f;
#pragma unroll
        for (int n = 0; n < 8; n++) { float v = acc1[n][rr]; s1 += v; s2 += v * v; }
        s1 = rowsum16(s1);
        s2 = rowsum16(s2);
        float mu = s1 * (1.f / 128.f);
        float var = fmaxf(s2 * (1.f / 128.f) - mu * mu, 0.f);
        float rs = rsqrtf(var + GEPS);
#pragma unroll
        for (int n = 0; n < 8; n++)
          acc1[n][rr] = (acc1[n][rr] - mu) * rs * lw[n] + lb[n];
      }
    }
  }

  // ---- H2 -> lsA (A-layout, wave-private rows; no barrier) ----
#pragma unroll
  for (int rr = 0; rr < 4; rr++)
#pragma unroll
    for (int n = 0; n < 8; n++) {
      lsA[(wv * 16 + q * 4 + rr) * 168 + n * 16 + c] =
          (unsigned short)f2bfu(acc0[n][rr]);
      lsA[(64 + wv * 16 + q * 4 + rr) * 168 + n * 16 + c] =
          (unsigned short)f2bfu(acc1[n][rr]);
    }

  // ---- fc2 (16-col padded tile), W2f loaded once per 2 tiles ----
  floatx4 o40 = (floatx4){0.f, 0.f, 0.f, 0.f};
  floatx4 o41 = (floatx4){0.f, 0.f, 0.f, 0.f};
#pragma unroll
  for (int kc = 0; kc < 4; kc++) {
    short8 a0 = *(const short8*)(pa0 + kc * 32);
    short8 a1 = *(const short8*)(pa1 + kc * 32);
    short8 b = *(const short8*)(W2f + kc * 512 + lane * 8);
    o40 = __builtin_amdgcn_mfma_f32_16x16x32_bf16(a0, b, o40, 0, 0, 0);
    o41 = __builtin_amdgcn_mfma_f32_16x16x32_bf16(a1, b, o41, 0, 0, 0);
  }
  if (c < NCLS) {
    float bias = fc2b[c];
#pragma unroll
    for (int rr = 0; rr < 4; rr++) {
      atomicAdd(out + (size_t)(b0 + wv * 16 + q * 4 + rr) * NCLS + c,
                (o40[rr] + bias) * 0.01f);
      atomicAdd(out + (size_t)(b0 + 64 + wv * 16 + q * 4 + rr) * NCLS + c,
                (o41[rr] + bias) * 0.01f);
    }
  }
}

// ---------------------------------------------------------------------------
extern "C" void kernel_launch(void* const* d_in, const int* in_sizes, int n_in,
                              void* d_out, int out_size, void* d_ws, size_t ws_size,
                              hipStream_t stream)
{
  (void)in_sizes; (void)n_in; (void)ws_size; (void)out_size;
  const float* x    = (const float*)d_in[0];
  const float* w1   = (const float*)d_in[1];
  const float* b1   = (const float*)d_in[2];
  const int*   perm = (const int*)d_in[3];
  const float* gn1w = (const float*)d_in[4];
  const float* gn1b = (const float*)d_in[5];
  const float* c2w  = (const float*)d_in[6];
  const float* c2b  = (const float*)d_in[7];
  const float* gn2w = (const float*)d_in[8];
  const float* gn2b = (const float*)d_in[9];
  const float* c3w  = (const float*)d_in[10];
  const float* c3b  = (const float*)d_in[11];
  const int*   swr  = (const int*)d_in[12];
  const float* E    = (const float*)d_in[13];
  const float* ln1w = (const float*)d_in[14];
  const float* ln1b = (const float*)d_in[15];
  const float* fc1w = (const float*)d_in[16];
  const float* fc1b = (const float*)d_in[17];
  const float* ln2w = (const float*)d_in[18];
  const float* ln2b = (const float*)d_in[19];
  const float* fc2w = (const float*)d_in[20];
  const float* fc2b = (const float*)d_in[21];
  float* out = (float*)d_out;

  // workspace layout:
  //   [0, 13.1MB)       : wT exp-logits bf16 [1600][B]
  //   [13.1MB, +4.10MB) : Bf (100*20480 shorts)
  //   then W1f 32,768 B, W2f 4,096 B
  const size_t W_BYTES = (size_t)NB * NRODT * 2;     // 13,107,200
  unsigned short* wTbuf = (unsigned short*)d_ws;
  unsigned short* Bfb   = (unsigned short*)((char*)d_ws + W_BYTES);
  unsigned short* W1fb  = (unsigned short*)((char*)d_ws + W_BYTES + 4096000);
  unsigned short* W2fb  = (unsigned short*)((char*)d_ws + W_BYTES + 4096000 + 32768);

  k01_prep<<<1600 + NFOR + 2 + 3, 256, 0, stream>>>(
      x, w1, b1, perm, gn1w, gn1b, c2w, c2b, gn2w, gn2b, c3w, c3b,
      E, swr, fc1w, fc2w, wTbuf, Bfb, W1fb, W2fb, out);
  dim3 g3(NB / 128, NFOR);
  k3_mfma<<<g3, 256, 0, stream>>>(wTbuf, swr, Bfb, W1fb, W2fb,
                                  ln1w, ln1b, fc1b, ln2w, ln2b, fc2b, out);
}